// Round 1
// 4488.913 us; speedup vs baseline: 1.2336x; 1.2336x over previous
//
#include <hip/hip_runtime.h>
#include <stdint.h>

typedef unsigned short u16;
typedef unsigned short u16x4 __attribute__((ext_vector_type(4)));
typedef unsigned short u16x8 __attribute__((ext_vector_type(8)));
typedef short bf16x8 __attribute__((ext_vector_type(8)));
typedef float f32x4 __attribute__((ext_vector_type(4)));

#define DEVINL __device__ __forceinline__

DEVINL float b2f(u16 u) {
  union { uint32_t u; float f; } c; c.u = ((uint32_t)u) << 16; return c.f;
}
DEVINL u16 f2b(float f) {
  union { float f; uint32_t u; } c; c.f = f;
  uint32_t u = c.u;
  u += 0x7fffu + ((u >> 16) & 1u);   // RNE
  return (u16)(u >> 16);
}

DEVINL void async16(const void* g, void* l) {
  __builtin_amdgcn_global_load_lds((__attribute__((address_space(1))) void*)g,
                                   (__attribute__((address_space(3))) void*)l,
                                   16, 0, 0);
}

DEVINL float rdlane(float v, int lane) {
  return __int_as_float(__builtin_amdgcn_readlane(__float_as_int(v), lane));
}

// =====================================================================
// f32 -> bf16 convert (weights). n % 4 == 0; grid covers n/4 threads.
// =====================================================================
__global__ __launch_bounds__(256) void cvt_f32_bf16(const float* __restrict__ s,
                                                    u16* __restrict__ d, int n4)
{
  int i = blockIdx.x * 256 + threadIdx.x;
  if (i >= n4) return;
  f32x4 v = *(const f32x4*)(s + (size_t)i * 4);
  u16x4 o;
  o[0] = f2b(v[0]); o[1] = f2b(v[1]); o[2] = f2b(v[2]); o[3] = f2b(v[3]);
  *(u16x4*)(d + (size_t)i * 4) = o;
}

// =====================================================================
// LayerNorm: f32 in -> bf16 out. One row (2048) per block.
// =====================================================================
__global__ __launch_bounds__(256) void ln_plain(const float* __restrict__ xin,
                                                const float* __restrict__ w,
                                                const float* __restrict__ b,
                                                u16* __restrict__ out)
{
  __shared__ float red[8];
  const size_t base = (size_t)blockIdx.x * 2048;
  const int tid = threadIdx.x;
  f32x4 r0 = *(const f32x4*)(xin + base + tid * 8);
  f32x4 r1 = *(const f32x4*)(xin + base + tid * 8 + 4);
  float f[8] = {r0[0], r0[1], r0[2], r0[3], r1[0], r1[1], r1[2], r1[3]};
  float s = 0.f, s2 = 0.f;
#pragma unroll
  for (int u = 0; u < 8; ++u) { s += f[u]; s2 += f[u] * f[u]; }
#pragma unroll
  for (int o = 32; o; o >>= 1) { s += __shfl_down(s, o, 64); s2 += __shfl_down(s2, o, 64); }
  if ((tid & 63) == 0) { red[tid >> 6] = s; red[4 + (tid >> 6)] = s2; }
  __syncthreads();
  s = red[0] + red[1] + red[2] + red[3];
  s2 = red[4] + red[5] + red[6] + red[7];
  const float m = s * (1.f / 2048.f);
  const float rs = rsqrtf(s2 * (1.f / 2048.f) - m * m + 1e-5f);
  u16x8 ov;
#pragma unroll
  for (int u = 0; u < 8; ++u) {
    int c = tid * 8 + u;
    ov[u] = f2b((f[u] - m) * rs * w[c] + b[c]);
  }
  *(u16x8*)(out + base + tid * 8) = ov;
}

// =====================================================================
// Fused LN + token-shift mix. xin is bf16 (x0/x1 in ws); params f32.
// prev = (t==0) ? f32 state : LN(xin[t-1]). stout: f32 last-row xn.
// =====================================================================
template <int NOUT>
__global__ __launch_bounds__(256) void ln_mix(const u16* __restrict__ xin,
                                              const float* __restrict__ lnw,
                                              const float* __restrict__ lnb,
                                              const float* __restrict__ prevst,
                                              const float* __restrict__ t0,
                                              const float* __restrict__ t1,
                                              const float* __restrict__ t2,
                                              const float* __restrict__ t3,
                                              u16* __restrict__ o0, u16* __restrict__ o1,
                                              u16* __restrict__ o2, u16* __restrict__ o3,
                                              float* __restrict__ stout)
{
  __shared__ float red[8];
  const int row = blockIdx.x;
  const int b = row >> 11, t = row & 2047;
  const int tid = threadIdx.x;
  const size_t base = (size_t)row * 2048;
  const int wv = tid >> 6, lane = tid & 63;

  u16x8 cr = *(const u16x8*)(xin + base + tid * 8);
  float cf[8];
  float s = 0.f, s2 = 0.f;
#pragma unroll
  for (int u = 0; u < 8; ++u) { cf[u] = b2f(cr[u]); s += cf[u]; s2 += cf[u] * cf[u]; }
#pragma unroll
  for (int o = 32; o; o >>= 1) { s += __shfl_down(s, o, 64); s2 += __shfl_down(s2, o, 64); }
  if (lane == 0) { red[wv] = s; red[4 + wv] = s2; }
  __syncthreads();
  s = red[0] + red[1] + red[2] + red[3];
  s2 = red[4] + red[5] + red[6] + red[7];
  float m = s * (1.f / 2048.f);
  float rs = rsqrtf(s2 * (1.f / 2048.f) - m * m + 1e-5f);
  float xn_t[8];
#pragma unroll
  for (int u = 0; u < 8; ++u) {
    int c = tid * 8 + u;
    xn_t[u] = (cf[u] - m) * rs * lnw[c] + lnb[c];
  }

  float xn_p[8];
  if (t == 0) {
#pragma unroll
    for (int u = 0; u < 8; ++u) xn_p[u] = prevst[(size_t)b * 2048 + tid * 8 + u];
  } else {
    u16x8 pr = *(const u16x8*)(xin + base - 2048 + tid * 8);
    float pf[8];
    float ps = 0.f, ps2 = 0.f;
#pragma unroll
    for (int u = 0; u < 8; ++u) { pf[u] = b2f(pr[u]); ps += pf[u]; ps2 += pf[u] * pf[u]; }
#pragma unroll
    for (int o = 32; o; o >>= 1) { ps += __shfl_down(ps, o, 64); ps2 += __shfl_down(ps2, o, 64); }
    __syncthreads();
    if (lane == 0) { red[wv] = ps; red[4 + wv] = ps2; }
    __syncthreads();
    ps = red[0] + red[1] + red[2] + red[3];
    ps2 = red[4] + red[5] + red[6] + red[7];
    float pm = ps * (1.f / 2048.f);
    float prs = rsqrtf(ps2 * (1.f / 2048.f) - pm * pm + 1e-5f);
#pragma unroll
    for (int u = 0; u < 8; ++u) {
      int c = tid * 8 + u;
      xn_p[u] = (pf[u] - pm) * prs * lnw[c] + lnb[c];
    }
  }

  u16x8 v0, v1, v2, v3;
#pragma unroll
  for (int u = 0; u < 8; ++u) {
    int c = tid * 8 + u;
    float a = xn_t[u], p = xn_p[u], d = a - p;
    v0[u] = f2b(p + d * t0[c]);
    v1[u] = f2b(p + d * t1[c]);
    if (NOUT == 4) {
      v2[u] = f2b(p + d * t2[c]);
      v3[u] = f2b(p + d * t3[c]);
    }
  }
  *(u16x8*)(o0 + base + tid * 8) = v0;
  *(u16x8*)(o1 + base + tid * 8) = v1;
  if (NOUT == 4) {
    *(u16x8*)(o2 + base + tid * 8) = v2;
    *(u16x8*)(o3 + base + tid * 8) = v3;
  }
  if (t == 2047) {
#pragma unroll
    for (int u = 0; u < 8; ++u) stout[(size_t)b * 2048 + tid * 8 + u] = xn_t[u];
  }
}

// =====================================================================
// bf16 GEMM: C[M,N] = epi( A[M,K] @ B[N,K]^T ), m97 structure.
// EPI: 0 plain, 1 silu, 2 relu^2, 3 sigmoid, 4 res+acc, 5 res+sig*acc
// F32OUT: write float32 output (else bf16).
// =====================================================================
template <int EPI, bool F32OUT>
__global__ __launch_bounds__(256) void gemm_bt(const u16* __restrict__ A,
                                               const u16* __restrict__ B,
                                               void* __restrict__ Cout,
                                               const u16* __restrict__ res,
                                               const u16* __restrict__ sig,
                                               int M, int N, int K)
{
  __shared__ short As[128 * 32];
  __shared__ short Bs[128 * 32];
  const int tid = threadIdx.x;
  const int lane = tid & 63;
  const int w = tid >> 6;
  const int wm = w >> 1, wn = w & 1;
  const int m0 = blockIdx.y * 128, n0 = blockIdx.x * 128;

  f32x4 acc[4][4];
#pragma unroll
  for (int mi = 0; mi < 4; ++mi)
#pragma unroll
    for (int ni = 0; ni < 4; ++ni) acc[mi][ni] = 0.f;

  const size_t a_goff = (size_t)(m0 + 32 * w + (lane >> 2)) * (size_t)K + (lane & 3) * 8;
  const size_t b_goff = (size_t)(n0 + 32 * w + (lane >> 2)) * (size_t)K + (lane & 3) * 8;
  short* asBase = &As[(2 * w) * 512];
  short* bsBase = &Bs[(2 * w) * 512];

  const int kq = (lane >> 4) * 8;
  const int am = wm * 64 + (lane & 15);
  const int bn = wn * 64 + (lane & 15);

  for (int k0 = 0; k0 < K; k0 += 32) {
    async16(A + a_goff + k0, asBase);
    async16(A + a_goff + (size_t)16 * K + k0, asBase + 512);
    async16(B + b_goff + k0, bsBase);
    async16(B + b_goff + (size_t)16 * K + k0, bsBase + 512);
    __syncthreads();
    bf16x8 af[4], bfr[4];
#pragma unroll
    for (int mi = 0; mi < 4; ++mi) af[mi] = *(const bf16x8*)&As[(am + mi * 16) * 32 + kq];
#pragma unroll
    for (int ni = 0; ni < 4; ++ni) bfr[ni] = *(const bf16x8*)&Bs[(bn + ni * 16) * 32 + kq];
#pragma unroll
    for (int mi = 0; mi < 4; ++mi)
#pragma unroll
      for (int ni = 0; ni < 4; ++ni)
        acc[mi][ni] = __builtin_amdgcn_mfma_f32_16x16x32_bf16(af[mi], bfr[ni], acc[mi][ni], 0, 0, 0);
    __syncthreads();
  }

  const int erow0 = m0 + wm * 64 + (lane >> 4) * 4;
  const int ecol0 = n0 + wn * 64 + (lane & 15);
#pragma unroll
  for (int mi = 0; mi < 4; ++mi) {
#pragma unroll
    for (int ni = 0; ni < 4; ++ni) {
#pragma unroll
      for (int r = 0; r < 4; ++r) {
        size_t idx = (size_t)(erow0 + mi * 16 + r) * (size_t)N + (ecol0 + ni * 16);
        float xv = acc[mi][ni][r];
        if (EPI == 1) xv = xv / (1.f + __expf(-xv));
        else if (EPI == 2) { float tt = fmaxf(xv, 0.f); xv = tt * tt; }
        else if (EPI == 3) xv = 1.f / (1.f + __expf(-xv));
        else if (EPI == 4) xv = b2f(res[idx]) + xv;
        else if (EPI == 5) xv = b2f(res[idx]) + b2f(sig[idx]) * xv;
        if (F32OUT) ((float*)Cout)[idx] = xv;
        else ((u16*)Cout)[idx] = f2b(xv);
      }
    }
  }
}

// =====================================================================
// WKV chunk-parallel scan.  T=2048 split into NC=16 chunks of L=128.
//
// Pass 1 (wkv_state): per (bh, chunk) wave, lane = state ROW i.
//   Accumulates chunk-local state from zero: no barriers, no cross-lane y.
// Combine (wkv_combine): per bh block, fold chunk locals sequentially:
//   S_in[c+1] = w^128 * S_in[c] + local[c]; locals buffer is rewritten
//   in-place to hold the chunk-start states; writes final wkv state out.
// Pass 2 (wkv_y): per (bh, chunk) wave, lane = state COLUMN j.
//   Full per-step recurrence + y output; r_i/k_i broadcast via readlane
//   (SGPR), u-term via 6-op shuffle reduce. y_t overwrites k_t in-place
//   (k_t is consumed strictly before the store; chunks are disjoint in t).
// =====================================================================
__global__ __launch_bounds__(256) void wkv_state(const u16* __restrict__ k,
                                                 const u16* __restrict__ v,
                                                 const float* __restrict__ td,
                                                 float* __restrict__ locals)
{
  const int tid = threadIdx.x;
  const int w = tid >> 6, lane = tid & 63;          // lane = state row i
  const int bh = blockIdx.x & 255;
  const int c = (blockIdx.x >> 8) * 4 + w;          // chunk 0..15
  const int b = bh >> 5, h = bh & 31;

  const float wdec = expf(-expf(td[h * 64 + lane]));
  float S[64];
#pragma unroll
  for (int j = 0; j < 64; ++j) S[j] = 0.f;

  const size_t rowbase = ((size_t)b * 2048 + (size_t)c * 128) * 2048 + h * 64;
  const u16* kp = k + rowbase + lane;
  const u16* vp = v + rowbase + lane;

  float kv = b2f(kp[0]), vv = b2f(vp[0]);
#pragma unroll 1
  for (int t = 0; t < 128; ++t) {
    float kn = 0.f, vn = 0.f;
    if (t < 127) { kn = b2f(kp[2048]); vn = b2f(vp[2048]); }
#pragma unroll
    for (int j = 0; j < 64; ++j) {
      float bv = rdlane(vv, j);                      // broadcast v_j
      S[j] = fmaf(S[j], wdec, kv * bv);              // S[i][j]*w_i + k_i*v_j
    }
    kp += 2048; vp += 2048;
    kv = kn; vv = vn;
  }
  // locals[bh][c][i*64+j], lane i writes its contiguous row
  float* lp = locals + ((size_t)bh * 16 + c) * 4096 + lane * 64;
#pragma unroll
  for (int j = 0; j < 64; j += 4) {
    f32x4 o; o[0] = S[j]; o[1] = S[j + 1]; o[2] = S[j + 2]; o[3] = S[j + 3];
    *(f32x4*)(lp + j) = o;
  }
}

__global__ __launch_bounds__(256) void wkv_combine(const float* __restrict__ st0,
                                                   const float* __restrict__ td,
                                                   float* __restrict__ locals,
                                                   float* __restrict__ stout)
{
  const int bh = blockIdx.x;
  const int h = bh & 31;
  const int tid = threadIdx.x;
  float S[16], wL[16];
#pragma unroll
  for (int q = 0; q < 16; ++q) {
    const int e = q * 256 + tid;                     // e = i*64+j
    S[q] = st0[(size_t)bh * 4096 + e];
    wL[q] = expf(-expf(td[h * 64 + (e >> 6)]) * 128.f);   // w_i^128 exact
  }
  float* lp = locals + (size_t)bh * 16 * 4096;
#pragma unroll 1
  for (int c = 0; c < 16; ++c) {
#pragma unroll
    for (int q = 0; q < 16; ++q) {
      const int e = q * 256 + tid;
      const float loc = lp[(size_t)c * 4096 + e];
      lp[(size_t)c * 4096 + e] = S[q];               // slot c := chunk-start state
      S[q] = fmaf(S[q], wL[q], loc);                 // advance past chunk c
    }
  }
#pragma unroll
  for (int q = 0; q < 16; ++q) stout[(size_t)bh * 4096 + q * 256 + tid] = S[q];
}

__global__ __launch_bounds__(256) void wkv_y(const u16* __restrict__ r,
                                             u16* ky,   // k in / y out, same buffer by design
                                             const u16* __restrict__ v,
                                             const float* __restrict__ td,
                                             const float* __restrict__ tf,
                                             const float* __restrict__ states)
{
  const int tid = threadIdx.x;
  const int w = tid >> 6, lane = tid & 63;          // lane = state column j
  const int bh = blockIdx.x & 255;
  const int c = (blockIdx.x >> 8) * 4 + w;          // chunk 0..15
  const int b = bh >> 5, h = bh & 31;

  const float wdec = expf(-expf(td[h * 64 + lane]));
  const float uv = tf[h * 64 + lane];
  float sw[64];                                      // row decays (uniform -> SGPR)
#pragma unroll
  for (int ii = 0; ii < 64; ++ii) sw[ii] = rdlane(wdec, ii);

  const float* sp = states + ((size_t)bh * 16 + c) * 4096 + lane;
  float S[64];
#pragma unroll
  for (int ii = 0; ii < 64; ++ii) S[ii] = sp[(size_t)ii * 64];

  const size_t rowbase = ((size_t)b * 2048 + (size_t)c * 128) * 2048 + h * 64;
  const u16* rp = r + rowbase + lane;
  const u16* vp = v + rowbase + lane;
  u16* kp = ky + rowbase + lane;

  float rv = b2f(rp[0]), kv = b2f(kp[0]), vv = b2f(vp[0]);
#pragma unroll 1
  for (int t = 0; t < 128; ++t) {
    float rn = 0.f, kn = 0.f, vn = 0.f;
    if (t < 127) { rn = b2f(rp[2048]); kn = b2f(kp[2048]); vn = b2f(vp[2048]); }
    // u-term: p = sum_i u_i r_i k_i  (lane as i), full-wave xor reduce
    float pl = uv * rv * kv;
    pl += __shfl_xor(pl, 1, 64);
    pl += __shfl_xor(pl, 2, 64);
    pl += __shfl_xor(pl, 4, 64);
    pl += __shfl_xor(pl, 8, 64);
    pl += __shfl_xor(pl, 16, 64);
    pl += __shfl_xor(pl, 32, 64);
    float y0 = 0.f, y1 = 0.f, y2 = 0.f, y3 = 0.f;    // 4 chains for ILP
#pragma unroll
    for (int ii = 0; ii < 64; ii += 4) {
      float br0 = rdlane(rv, ii),     bk0 = rdlane(kv, ii);
      y0 = fmaf(br0, S[ii], y0);      S[ii]     = fmaf(S[ii],     sw[ii],     bk0 * vv);
      float br1 = rdlane(rv, ii + 1), bk1 = rdlane(kv, ii + 1);
      y1 = fmaf(br1, S[ii + 1], y1);  S[ii + 1] = fmaf(S[ii + 1], sw[ii + 1], bk1 * vv);
      float br2 = rdlane(rv, ii + 2), bk2 = rdlane(kv, ii + 2);
      y2 = fmaf(br2, S[ii + 2], y2);  S[ii + 2] = fmaf(S[ii + 2], sw[ii + 2], bk2 * vv);
      float br3 = rdlane(rv, ii + 3), bk3 = rdlane(kv, ii + 3);
      y3 = fmaf(br3, S[ii + 3], y3);  S[ii + 3] = fmaf(S[ii + 3], sw[ii + 3], bk3 * vv);
    }
    float yy = ((y0 + y1) + (y2 + y3)) + pl * vv;
    kp[0] = f2b(yy);                                 // y_t overwrites consumed k_t
    rp += 2048; kp += 2048; vp += 2048;
    rv = rn; kv = kn; vv = vn;
  }
}

// =====================================================================
// GroupNorm per (b,t,h) over HS=64 (with /8 prescale), then * g.
// =====================================================================
__global__ __launch_bounds__(256) void gn_mul(const u16* __restrict__ y,
                                              const float* __restrict__ lnxw,
                                              const float* __restrict__ lnxb,
                                              const u16* __restrict__ g,
                                              u16* __restrict__ og)
{
  const int tid = threadIdx.x;
  const int wv = tid >> 6, j = tid & 63;
  const size_t gidx = (size_t)blockIdx.x * 4 + wv;
  const size_t bt = gidx >> 5;
  const int h = (int)(gidx & 31);
  const int c = h * 64 + j;
  float o = b2f(y[bt * 2048 + c]) * 0.125f;
  float s = o;
#pragma unroll
  for (int off = 32; off; off >>= 1) s += __shfl_xor(s, off, 64);
  const float m = s * (1.f / 64.f);
  const float d = o - m;
  float s2 = d * d;
#pragma unroll
  for (int off = 32; off; off >>= 1) s2 += __shfl_xor(s2, off, 64);
  const float var = s2 * (1.f / 64.f);
  float on = d * rsqrtf(var + 1e-5f);
  on = on * lnxw[c] + lnxb[c];
  og[bt * 2048 + c] = f2b(on * b2f(g[bt * 2048 + c]));
}

// =====================================================================
extern "C" void kernel_launch(void* const* d_in, const int* in_sizes, int n_in,
                              void* d_out, int out_size, void* d_ws, size_t ws_size,
                              hipStream_t stream)
{
  const float* x    = (const float*)d_in[0];
  const float* att0 = (const float*)d_in[1];
  const float* ffn0 = (const float*)d_in[2];
  const float* wkv0 = (const float*)d_in[3];
  const float* ln0w = (const float*)d_in[4];
  const float* ln0b = (const float*)d_in[5];
  const float* ln1w = (const float*)d_in[6];
  const float* ln1b = (const float*)d_in[7];
  const float* ln2w = (const float*)d_in[8];
  const float* ln2b = (const float*)d_in[9];
  const float* tmk  = (const float*)d_in[10];
  const float* tmv  = (const float*)d_in[11];
  const float* tmr  = (const float*)d_in[12];
  const float* tmg  = (const float*)d_in[13];
  const float* td   = (const float*)d_in[14];
  const float* tf   = (const float*)d_in[15];
  const float* Wg   = (const float*)d_in[16];
  const float* Wr   = (const float*)d_in[17];
  const float* Wk   = (const float*)d_in[18];
  const float* Wv   = (const float*)d_in[19];
  const float* Wo   = (const float*)d_in[20];
  const float* lnxw = (const float*)d_in[21];
  const float* lnxb = (const float*)d_in[22];
  const float* ftmk = (const float*)d_in[23];
  const float* ftmr = (const float*)d_in[24];
  const float* fWk  = (const float*)d_in[25];
  const float* fWr  = (const float*)d_in[26];
  const float* fWv  = (const float*)d_in[27];

  // ws layout (u16 elems; 1 MiB = 524288). Peak 320 MiB (known safe).
  u16* ws = (u16*)d_ws;
  auto seg = [&](size_t mib) { return ws + mib * 524288ull; };
  u16* A_ = seg(0);     // x0 -> x1 (bf16)
  u16* B_ = seg(64);
  u16* C_ = seg(128);
  u16* D_ = seg(192);
  u16* WT = seg(256);   // 64 MiB weight region (re-packed per phase)
  // attention: Wr,Wk,Wv,Wg,Wo bf16 (8 MiB each)
  u16* w_r = WT;
  u16* w_k = WT + 4194304ull;
  u16* w_v = WT + 8388608ull;
  u16* w_g = WT + 12582912ull;
  u16* w_o = WT + 16777216ull;
  // ffn: fWr (8 MiB), fWk (28), fWv (28)
  u16* w_fr = WT;
  u16* w_fk = WT + 4194304ull;
  u16* w_fv = WT + 18874368ull;
  u16* KK = C_;         // 28 MiB kk chunk (C_ dead by then)

  float* out_x   = (float*)d_out;
  float* out_ffn = out_x + 33554432ull;
  float* out_att = out_ffn + 16384ull;
  float* out_wkv = out_att + 16384ull;
  // d_out x-region (128 MiB f32) as scratch:
  u16* OUT0 = (u16*)d_out;              // xg, then wkv chunk-state buffer
  u16* OUT1 = OUT0 + 33554432ull;       // rb
  float* wkvloc = (float*)d_out;        // 64 MiB: locals/chunk-in states [bh][16][4096]

  const dim3 b256(256);
  const dim3 g2048(16, 128);
  const dim3 gKK(56, 16);   // N=7168, M=2048 chunk
  const dim3 gKV(16, 16);   // N=2048, M=2048 chunk

  // ---- attention ----
  cvt_f32_bf16<<<4096, b256, 0, stream>>>(Wr, w_r, 1048576);
  cvt_f32_bf16<<<4096, b256, 0, stream>>>(Wk, w_k, 1048576);
  cvt_f32_bf16<<<4096, b256, 0, stream>>>(Wv, w_v, 1048576);
  cvt_f32_bf16<<<4096, b256, 0, stream>>>(Wg, w_g, 1048576);
  cvt_f32_bf16<<<4096, b256, 0, stream>>>(Wo, w_o, 1048576);
  ln_plain<<<16384, b256, 0, stream>>>(x, ln0w, ln0b, A_);
  ln_mix<4><<<16384, b256, 0, stream>>>(A_, ln1w, ln1b, att0, tmk, tmv, tmr, tmg,
                                        B_, C_, D_, OUT0, out_att); // xk,xv,xr,xg
  gemm_bt<0,false><<<g2048, b256, 0, stream>>>(D_,   w_r, OUT1, nullptr, nullptr, 16384, 2048, 2048); // rb
  gemm_bt<0,false><<<g2048, b256, 0, stream>>>(B_,   w_k, D_,   nullptr, nullptr, 16384, 2048, 2048); // kb
  gemm_bt<0,false><<<g2048, b256, 0, stream>>>(C_,   w_v, B_,   nullptr, nullptr, 16384, 2048, 2048); // vb
  gemm_bt<1,false><<<g2048, b256, 0, stream>>>(OUT0, w_g, C_,   nullptr, nullptr, 16384, 2048, 2048); // gb (silu)
  // chunk-parallel wkv (OUT0/xg is dead after the g-gemm -> reuse as states)
  wkv_state<<<1024, b256, 0, stream>>>(D_, B_, td, wkvloc);
  wkv_combine<<<256, b256, 0, stream>>>(wkv0, td, wkvloc, out_wkv);
  wkv_y<<<1024, b256, 0, stream>>>(OUT1, D_, B_, td, tf, wkvloc);   // y -> D_ (over kb)
  gn_mul<<<131072, b256, 0, stream>>>(D_, lnxw, lnxb, C_, B_);      // og -> B_
  gemm_bt<4,false><<<g2048, b256, 0, stream>>>(B_, w_o, A_, A_, nullptr, 16384, 2048, 2048); // x1 = x0+att

  // ---- ffn ----
  ln_mix<2><<<16384, b256, 0, stream>>>(A_, ln2w, ln2b, ffn0, ftmk, ftmr, nullptr, nullptr,
                                        B_, C_, nullptr, nullptr, out_ffn);  // xk2=B_, xr2=C_
  cvt_f32_bf16<<<4096, b256, 0, stream>>>(fWr, w_fr, 1048576);
  gemm_bt<3,false><<<g2048, b256, 0, stream>>>(C_, w_fr, D_, nullptr, nullptr, 16384, 2048, 2048); // rr (sigmoid)
  cvt_f32_bf16<<<14336, b256, 0, stream>>>(fWk, w_fk, 3670016);
  cvt_f32_bf16<<<14336, b256, 0, stream>>>(fWv, w_fv, 3670016);
  for (int h = 0; h < 8; ++h) {
    const size_t off = (size_t)h * 2048 * 2048;
    gemm_bt<2,false><<<gKK, b256, 0, stream>>>(B_ + off, w_fk, KK, nullptr, nullptr,
                                               2048, 7168, 2048);                 // kk chunk (relu^2)
    gemm_bt<5,true><<<gKV, b256, 0, stream>>>(KK, w_fv, out_x + off, A_ + off, D_ + off,
                                              2048, 2048, 7168);                  // x + sig*kv (f32 out)
  }
}

// Round 2
// 3004.506 us; speedup vs baseline: 1.8431x; 1.4941x over previous
//
#include <hip/hip_runtime.h>
#include <stdint.h>

typedef unsigned short u16;
typedef unsigned short u16x4 __attribute__((ext_vector_type(4)));
typedef unsigned short u16x8 __attribute__((ext_vector_type(8)));
typedef short bf16x8 __attribute__((ext_vector_type(8)));
typedef float f32x4 __attribute__((ext_vector_type(4)));

#define DEVINL __device__ __forceinline__

DEVINL float b2f(u16 u) {
  union { uint32_t u; float f; } c; c.u = ((uint32_t)u) << 16; return c.f;
}
DEVINL u16 f2b(float f) {
  union { float f; uint32_t u; } c; c.f = f;
  uint32_t u = c.u;
  u += 0x7fffu + ((u >> 16) & 1u);   // RNE
  return (u16)(u >> 16);
}

DEVINL void async16(const void* g, void* l) {
  __builtin_amdgcn_global_load_lds((__attribute__((address_space(1))) void*)g,
                                   (__attribute__((address_space(3))) void*)l,
                                   16, 0, 0);
}

DEVINL float rdlane(float v, int lane) {
  return __int_as_float(__builtin_amdgcn_readlane(__float_as_int(v), lane));
}

// =====================================================================
// f32 -> bf16 convert (weights). n % 4 == 0; grid covers n/4 threads.
// =====================================================================
__global__ __launch_bounds__(256) void cvt_f32_bf16(const float* __restrict__ s,
                                                    u16* __restrict__ d, int n4)
{
  int i = blockIdx.x * 256 + threadIdx.x;
  if (i >= n4) return;
  f32x4 v = *(const f32x4*)(s + (size_t)i * 4);
  u16x4 o;
  o[0] = f2b(v[0]); o[1] = f2b(v[1]); o[2] = f2b(v[2]); o[3] = f2b(v[3]);
  *(u16x4*)(d + (size_t)i * 4) = o;
}

// =====================================================================
// LayerNorm: f32 in -> bf16 out. One row (2048) per block.
// =====================================================================
__global__ __launch_bounds__(256) void ln_plain(const float* __restrict__ xin,
                                                const float* __restrict__ w,
                                                const float* __restrict__ b,
                                                u16* __restrict__ out)
{
  __shared__ float red[8];
  const size_t base = (size_t)blockIdx.x * 2048;
  const int tid = threadIdx.x;
  f32x4 r0 = *(const f32x4*)(xin + base + tid * 8);
  f32x4 r1 = *(const f32x4*)(xin + base + tid * 8 + 4);
  float f[8] = {r0[0], r0[1], r0[2], r0[3], r1[0], r1[1], r1[2], r1[3]};
  float s = 0.f, s2 = 0.f;
#pragma unroll
  for (int u = 0; u < 8; ++u) { s += f[u]; s2 += f[u] * f[u]; }
#pragma unroll
  for (int o = 32; o; o >>= 1) { s += __shfl_down(s, o, 64); s2 += __shfl_down(s2, o, 64); }
  if ((tid & 63) == 0) { red[tid >> 6] = s; red[4 + (tid >> 6)] = s2; }
  __syncthreads();
  s = red[0] + red[1] + red[2] + red[3];
  s2 = red[4] + red[5] + red[6] + red[7];
  const float m = s * (1.f / 2048.f);
  const float rs = rsqrtf(s2 * (1.f / 2048.f) - m * m + 1e-5f);
  u16x8 ov;
#pragma unroll
  for (int u = 0; u < 8; ++u) {
    int c = tid * 8 + u;
    ov[u] = f2b((f[u] - m) * rs * w[c] + b[c]);
  }
  *(u16x8*)(out + base + tid * 8) = ov;
}

// =====================================================================
// Fused LN + token-shift mix. xin is bf16 (x0/x1 in ws); params f32.
// prev = (t==0) ? f32 state : LN(xin[t-1]). stout: f32 last-row xn.
// =====================================================================
template <int NOUT>
__global__ __launch_bounds__(256) void ln_mix(const u16* __restrict__ xin,
                                              const float* __restrict__ lnw,
                                              const float* __restrict__ lnb,
                                              const float* __restrict__ prevst,
                                              const float* __restrict__ t0,
                                              const float* __restrict__ t1,
                                              const float* __restrict__ t2,
                                              const float* __restrict__ t3,
                                              u16* __restrict__ o0, u16* __restrict__ o1,
                                              u16* __restrict__ o2, u16* __restrict__ o3,
                                              float* __restrict__ stout)
{
  __shared__ float red[8];
  const int row = blockIdx.x;
  const int b = row >> 11, t = row & 2047;
  const int tid = threadIdx.x;
  const size_t base = (size_t)row * 2048;
  const int wv = tid >> 6, lane = tid & 63;

  u16x8 cr = *(const u16x8*)(xin + base + tid * 8);
  float cf[8];
  float s = 0.f, s2 = 0.f;
#pragma unroll
  for (int u = 0; u < 8; ++u) { cf[u] = b2f(cr[u]); s += cf[u]; s2 += cf[u] * cf[u]; }
#pragma unroll
  for (int o = 32; o; o >>= 1) { s += __shfl_down(s, o, 64); s2 += __shfl_down(s2, o, 64); }
  if (lane == 0) { red[wv] = s; red[4 + wv] = s2; }
  __syncthreads();
  s = red[0] + red[1] + red[2] + red[3];
  s2 = red[4] + red[5] + red[6] + red[7];
  float m = s * (1.f / 2048.f);
  float rs = rsqrtf(s2 * (1.f / 2048.f) - m * m + 1e-5f);
  float xn_t[8];
#pragma unroll
  for (int u = 0; u < 8; ++u) {
    int c = tid * 8 + u;
    xn_t[u] = (cf[u] - m) * rs * lnw[c] + lnb[c];
  }

  float xn_p[8];
  if (t == 0) {
#pragma unroll
    for (int u = 0; u < 8; ++u) xn_p[u] = prevst[(size_t)b * 2048 + tid * 8 + u];
  } else {
    u16x8 pr = *(const u16x8*)(xin + base - 2048 + tid * 8);
    float pf[8];
    float ps = 0.f, ps2 = 0.f;
#pragma unroll
    for (int u = 0; u < 8; ++u) { pf[u] = b2f(pr[u]); ps += pf[u]; ps2 += pf[u] * pf[u]; }
#pragma unroll
    for (int o = 32; o; o >>= 1) { ps += __shfl_down(ps, o, 64); ps2 += __shfl_down(ps2, o, 64); }
    __syncthreads();
    if (lane == 0) { red[wv] = ps; red[4 + wv] = ps2; }
    __syncthreads();
    ps = red[0] + red[1] + red[2] + red[3];
    ps2 = red[4] + red[5] + red[6] + red[7];
    float pm = ps * (1.f / 2048.f);
    float prs = rsqrtf(ps2 * (1.f / 2048.f) - pm * pm + 1e-5f);
#pragma unroll
    for (int u = 0; u < 8; ++u) {
      int c = tid * 8 + u;
      xn_p[u] = (pf[u] - pm) * prs * lnw[c] + lnb[c];
    }
  }

  u16x8 v0, v1, v2, v3;
#pragma unroll
  for (int u = 0; u < 8; ++u) {
    int c = tid * 8 + u;
    float a = xn_t[u], p = xn_p[u], d = a - p;
    v0[u] = f2b(p + d * t0[c]);
    v1[u] = f2b(p + d * t1[c]);
    if (NOUT == 4) {
      v2[u] = f2b(p + d * t2[c]);
      v3[u] = f2b(p + d * t3[c]);
    }
  }
  *(u16x8*)(o0 + base + tid * 8) = v0;
  *(u16x8*)(o1 + base + tid * 8) = v1;
  if (NOUT == 4) {
    *(u16x8*)(o2 + base + tid * 8) = v2;
    *(u16x8*)(o3 + base + tid * 8) = v3;
  }
  if (t == 2047) {
#pragma unroll
    for (int u = 0; u < 8; ++u) stout[(size_t)b * 2048 + tid * 8 + u] = xn_t[u];
  }
}

// =====================================================================
// 256x256-tile 8-phase bf16 GEMM (T1+T2+T3+T4+T5 template).
// C[M,N] = epi( A[M,K] @ B[N,K]^T ), strides lda/ldb/ldc in elements.
// 512 thr = 8 waves (2M x 4N); per-wave out 128x64; BK=64, 2 K-tiles/iter.
// LDS 128 KiB: 2 dbuf x {Ah0,Ah1,Bh0,Bh1} halves of 16 KiB.
// Swizzle: byte-groups of 16 XORed with (row&7) on BOTH the global
// source of global_load_lds (linear LDS dest) and the ds_read address.
// EPI: 0 plain, 1 silu, 2 relu^2, 3 sigmoid, 4 res+acc (bf16 out),
//      6 f32 store, 7 f32 +=, 8 f32 final res+sig*(prev+acc).
// =====================================================================
#define BAR() __builtin_amdgcn_s_barrier()
#define WAIT_LGKM0() { asm volatile("s_waitcnt lgkmcnt(0)" ::: "memory"); \
                       __builtin_amdgcn_sched_barrier(0); }

template <int EPI>
__global__ __launch_bounds__(512, 2) void gemm256(const u16* __restrict__ A,
                                                  const u16* __restrict__ Bw,
                                                  void* __restrict__ Cout,
                                                  const u16* __restrict__ res,
                                                  const u16* __restrict__ sig,
                                                  int M, int N, int K,
                                                  int lda, int ldb, int ldc)
{
  __shared__ short lds[65536];   // 128 KiB
  const int tid = threadIdx.x;
  const int lane = tid & 63;
  const int wid = tid >> 6;
  const int wm = wid >> 2, wn = wid & 3;

  // bijective XCD swizzle (m204); consecutive-in-XCD share bx (B panel L2-hot)
  const int nby = M >> 8;
  const int nwg = (N >> 8) * nby;
  const int q8 = nwg >> 3, r8 = nwg & 7;
  const int xcd = (int)blockIdx.x & 7, rest = (int)blockIdx.x >> 3;
  const int swz = (xcd < r8 ? xcd * (q8 + 1) : r8 * (q8 + 1) + (xcd - r8) * q8) + rest;
  const int bx = swz / nby, by = swz - bx * nby;
  const int m0 = by << 8, n0 = bx << 8;

  f32x4 acc[8][4];
#pragma unroll
  for (int i = 0; i < 8; ++i)
#pragma unroll
    for (int j = 0; j < 4; ++j) acc[i][j] = 0.f;

  // ---- staging constants (pre-swizzled global source, linear LDS dest) ----
  const int srow = tid >> 3;                       // 0..63
  const int sgrp = (tid & 7) ^ (srow & 7);         // swizzled 16B group
  const u16* Abase = A + (size_t)(m0 + srow) * lda + sgrp * 8;
  const u16* Bbase = Bw + (size_t)(n0 + srow) * ldb + sgrp * 8;
  short* ldsS = &lds[tid * 8];

#define STAGE(db, ISB, half, kt)                                           \
  {                                                                        \
    const u16* gp_ = (ISB ? Bbase + (size_t)((half) * 128) * ldb           \
                          : Abase + (size_t)((half) * 128) * lda) +        \
                     (size_t)(kt) * 64;                                    \
    const int ldx_ = (ISB ? ldb : lda);                                    \
    short* lp_ = ldsS + (db) * 32768 + (ISB) * 16384 + (half) * 8192;      \
    async16(gp_, lp_);                                                     \
    async16(gp_ + (size_t)64 * ldx_, lp_ + 4096);                          \
  }

  // ---- reader constants ----
  const int rlo = lane & 15;
  const int kq4 = lane >> 4;                       // 0..3

  bf16x8 afr[4][2], b0r[2][2], b1r[2][2];

#define LDA_Q(db, qm)                                                      \
  {                                                                        \
    const short* ab_ = &lds[(db) * 32768 + wm * 8192];                     \
    _Pragma("unroll") for (int fq = 0; fq < 4; ++fq) {                     \
      const int row_ = (qm) * 64 + fq * 16 + rlo;                          \
      _Pragma("unroll") for (int kh = 0; kh < 2; ++kh) {                   \
        const int g_ = (kh * 4 + kq4) ^ (row_ & 7);                        \
        afr[fq][kh] = *(const bf16x8*)&ab_[row_ * 64 + g_ * 8];            \
      }                                                                    \
    }                                                                      \
  }

#define LDB_Q(db, qn, dst)                                                 \
  {                                                                        \
    const short* bb_ = &lds[(db) * 32768 + 16384 + (wn >> 1) * 8192];      \
    _Pragma("unroll") for (int fr = 0; fr < 2; ++fr) {                     \
      const int row_ = (wn & 1) * 64 + (qn) * 32 + fr * 16 + rlo;          \
      _Pragma("unroll") for (int kh = 0; kh < 2; ++kh) {                   \
        const int g_ = (kh * 4 + kq4) ^ (row_ & 7);                        \
        dst[fr][kh] = *(const bf16x8*)&bb_[row_ * 64 + g_ * 8];            \
      }                                                                    \
    }                                                                      \
  }

#define MFMA_Q(qm, qn, bsrc)                                               \
  {                                                                        \
    __builtin_amdgcn_s_setprio(1);                                         \
    _Pragma("unroll") for (int fq = 0; fq < 4; ++fq)                       \
      _Pragma("unroll") for (int fr = 0; fr < 2; ++fr)                     \
        _Pragma("unroll") for (int kh = 0; kh < 2; ++kh)                   \
          acc[(qm) * 4 + fq][(qn) * 2 + fr] =                              \
              __builtin_amdgcn_mfma_f32_16x16x32_bf16(                     \
                  afr[fq][kh], bsrc[fr][kh],                               \
                  acc[(qm) * 4 + fq][(qn) * 2 + fr], 0, 0, 0);             \
    __builtin_amdgcn_s_setprio(0);                                         \
  }

  const int nit = K >> 7;      // iters; 2 K-tiles (BK=64) per iter
  // prologue: kt0 -> db0 (4 halves), kt1 Bh0/Bh1 -> db1
  STAGE(0, 0, 0, 0); STAGE(0, 0, 1, 0); STAGE(0, 1, 0, 0); STAGE(0, 1, 1, 0);
  STAGE(1, 1, 0, 1); STAGE(1, 1, 1, 1);
  asm volatile("s_waitcnt vmcnt(4)" ::: "memory");
  BAR();

#pragma unroll 1
  for (int it = 0; it < nit; ++it) {
    const int k1 = 2 * it + 1;
    const int k2 = (2 * it + 2 < 2 * nit) ? 2 * it + 2 : 0;   // clamp: dead-region garbage
    const int k3 = (2 * it + 3 < 2 * nit) ? 2 * it + 3 : 0;

    // ph1: read db0 A[q0], B[q0]; stage db1.Ah0(k1)
    LDA_Q(0, 0); LDB_Q(0, 0, b0r);
    STAGE(1, 0, 0, k1);
    asm volatile("s_waitcnt lgkmcnt(8)" ::: "memory");
    BAR(); WAIT_LGKM0();
    MFMA_Q(0, 0, b0r);
    BAR();

    // ph2: read db0 B[q1]; stage db1.Ah1(k1)
    LDB_Q(0, 1, b1r);
    STAGE(1, 0, 1, k1);
    BAR(); WAIT_LGKM0();
    MFMA_Q(0, 1, b1r);
    BAR();

    // ph3: read db0 A[q1]; stage db0.Bh0(k2)
    LDA_Q(0, 1);
    STAGE(0, 1, 0, k2);
    BAR(); WAIT_LGKM0();
    MFMA_Q(1, 1, b1r);
    BAR();

    // ph4: stage db0.Bh1(k2); MFMA (1,0); counted vmcnt -> db1 ready
    STAGE(0, 1, 1, k2);
    BAR();
    MFMA_Q(1, 0, b0r);
    asm volatile("s_waitcnt vmcnt(4)" ::: "memory");
    BAR();

    // ph5: read db1 A[q0], B[q0]; stage db0.Ah0(k2)
    LDA_Q(1, 0); LDB_Q(1, 0, b0r);
    STAGE(0, 0, 0, k2);
    asm volatile("s_waitcnt lgkmcnt(8)" ::: "memory");
    BAR(); WAIT_LGKM0();
    MFMA_Q(0, 0, b0r);
    BAR();

    // ph6: read db1 B[q1]; stage db0.Ah1(k2)
    LDB_Q(1, 1, b1r);
    STAGE(0, 0, 1, k2);
    BAR(); WAIT_LGKM0();
    MFMA_Q(0, 1, b1r);
    BAR();

    // ph7: read db1 A[q1]; stage db1.Bh0(k3)
    LDA_Q(1, 1);
    STAGE(1, 1, 0, k3);
    BAR(); WAIT_LGKM0();
    MFMA_Q(1, 1, b1r);
    BAR();

    // ph8: stage db1.Bh1(k3); MFMA (1,0); counted vmcnt -> db0 ready
    STAGE(1, 1, 1, k3);
    BAR();
    MFMA_Q(1, 0, b0r);
    asm volatile("s_waitcnt vmcnt(4)" ::: "memory");
    BAR();
  }
  asm volatile("s_waitcnt vmcnt(0)" ::: "memory");

  // ---- epilogue ----
  const int erow0 = m0 + wm * 128 + (lane >> 4) * 4;
  const int ecol0 = n0 + wn * 64 + (lane & 15);
#pragma unroll
  for (int fm = 0; fm < 8; ++fm) {
#pragma unroll
    for (int fn = 0; fn < 4; ++fn) {
#pragma unroll
      for (int r = 0; r < 4; ++r) {
        size_t idx = (size_t)(erow0 + fm * 16 + r) * (size_t)ldc + (ecol0 + fn * 16);
        float xv = acc[fm][fn][r];
        if (EPI == 1) xv = xv / (1.f + __expf(-xv));
        else if (EPI == 2) { float tt = fmaxf(xv, 0.f); xv = tt * tt; }
        else if (EPI == 3) xv = 1.f / (1.f + __expf(-xv));
        else if (EPI == 4) xv = b2f(res[idx]) + xv;
        if (EPI == 6) ((float*)Cout)[idx] = xv;
        else if (EPI == 7) { float* cp = (float*)Cout; cp[idx] += xv; }
        else if (EPI == 8) {
          float* cp = (float*)Cout;
          cp[idx] = b2f(res[idx]) + b2f(sig[idx]) * (cp[idx] + xv);
        } else ((u16*)Cout)[idx] = f2b(xv);
      }
    }
  }
}

// =====================================================================
// WKV chunk-parallel scan (unchanged from previous round).
// =====================================================================
__global__ __launch_bounds__(256) void wkv_state(const u16* __restrict__ k,
                                                 const u16* __restrict__ v,
                                                 const float* __restrict__ td,
                                                 float* __restrict__ locals)
{
  const int tid = threadIdx.x;
  const int w = tid >> 6, lane = tid & 63;          // lane = state row i
  const int bh = blockIdx.x & 255;
  const int c = (blockIdx.x >> 8) * 4 + w;          // chunk 0..15
  const int b = bh >> 5, h = bh & 31;

  const float wdec = expf(-expf(td[h * 64 + lane]));
  float S[64];
#pragma unroll
  for (int j = 0; j < 64; ++j) S[j] = 0.f;

  const size_t rowbase = ((size_t)b * 2048 + (size_t)c * 128) * 2048 + h * 64;
  const u16* kp = k + rowbase + lane;
  const u16* vp = v + rowbase + lane;

  float kv = b2f(kp[0]), vv = b2f(vp[0]);
#pragma unroll 1
  for (int t = 0; t < 128; ++t) {
    float kn = 0.f, vn = 0.f;
    if (t < 127) { kn = b2f(kp[2048]); vn = b2f(vp[2048]); }
#pragma unroll
    for (int j = 0; j < 64; ++j) {
      float bv = rdlane(vv, j);
      S[j] = fmaf(S[j], wdec, kv * bv);
    }
    kp += 2048; vp += 2048;
    kv = kn; vv = vn;
  }
  float* lp = locals + ((size_t)bh * 16 + c) * 4096 + lane * 64;
#pragma unroll
  for (int j = 0; j < 64; j += 4) {
    f32x4 o; o[0] = S[j]; o[1] = S[j + 1]; o[2] = S[j + 2]; o[3] = S[j + 3];
    *(f32x4*)(lp + j) = o;
  }
}

__global__ __launch_bounds__(256) void wkv_combine(const float* __restrict__ st0,
                                                   const float* __restrict__ td,
                                                   float* __restrict__ locals,
                                                   float* __restrict__ stout)
{
  const int bh = blockIdx.x;
  const int h = bh & 31;
  const int tid = threadIdx.x;
  float S[16], wL[16];
#pragma unroll
  for (int q = 0; q < 16; ++q) {
    const int e = q * 256 + tid;
    S[q] = st0[(size_t)bh * 4096 + e];
    wL[q] = expf(-expf(td[h * 64 + (e >> 6)]) * 128.f);
  }
  float* lp = locals + (size_t)bh * 16 * 4096;
#pragma unroll 1
  for (int c = 0; c < 16; ++c) {
#pragma unroll
    for (int q = 0; q < 16; ++q) {
      const int e = q * 256 + tid;
      const float loc = lp[(size_t)c * 4096 + e];
      lp[(size_t)c * 4096 + e] = S[q];
      S[q] = fmaf(S[q], wL[q], loc);
    }
  }
#pragma unroll
  for (int q = 0; q < 16; ++q) stout[(size_t)bh * 4096 + q * 256 + tid] = S[q];
}

__global__ __launch_bounds__(256) void wkv_y(const u16* __restrict__ r,
                                             u16* ky,   // k in / y out, same buffer
                                             const u16* __restrict__ v,
                                             const float* __restrict__ td,
                                             const float* __restrict__ tf,
                                             const float* __restrict__ states)
{
  const int tid = threadIdx.x;
  const int w = tid >> 6, lane = tid & 63;          // lane = state column j
  const int bh = blockIdx.x & 255;
  const int c = (blockIdx.x >> 8) * 4 + w;
  const int b = bh >> 5, h = bh & 31;

  const float wdec = expf(-expf(td[h * 64 + lane]));
  const float uv = tf[h * 64 + lane];
  float sw[64];
#pragma unroll
  for (int ii = 0; ii < 64; ++ii) sw[ii] = rdlane(wdec, ii);

  const float* sp = states + ((size_t)bh * 16 + c) * 4096 + lane;
  float S[64];
#pragma unroll
  for (int ii = 0; ii < 64; ++ii) S[ii] = sp[(size_t)ii * 64];

  const size_t rowbase = ((size_t)b * 2048 + (size_t)c * 128) * 2048 + h * 64;
  const u16* rp = r + rowbase + lane;
  const u16* vp = v + rowbase + lane;
  u16* kp = ky + rowbase + lane;

  float rv = b2f(rp[0]), kv = b2f(kp[0]), vv = b2f(vp[0]);
#pragma unroll 1
  for (int t = 0; t < 128; ++t) {
    float rn = 0.f, kn = 0.f, vn = 0.f;
    if (t < 127) { rn = b2f(rp[2048]); kn = b2f(kp[2048]); vn = b2f(vp[2048]); }
    float pl = uv * rv * kv;
    pl += __shfl_xor(pl, 1, 64);
    pl += __shfl_xor(pl, 2, 64);
    pl += __shfl_xor(pl, 4, 64);
    pl += __shfl_xor(pl, 8, 64);
    pl += __shfl_xor(pl, 16, 64);
    pl += __shfl_xor(pl, 32, 64);
    float y0 = 0.f, y1 = 0.f, y2 = 0.f, y3 = 0.f;
#pragma unroll
    for (int ii = 0; ii < 64; ii += 4) {
      float br0 = rdlane(rv, ii),     bk0 = rdlane(kv, ii);
      y0 = fmaf(br0, S[ii], y0);      S[ii]     = fmaf(S[ii],     sw[ii],     bk0 * vv);
      float br1 = rdlane(rv, ii + 1), bk1 = rdlane(kv, ii + 1);
      y1 = fmaf(br1, S[ii + 1], y1);  S[ii + 1] = fmaf(S[ii + 1], sw[ii + 1], bk1 * vv);
      float br2 = rdlane(rv, ii + 2), bk2 = rdlane(kv, ii + 2);
      y2 = fmaf(br2, S[ii + 2], y2);  S[ii + 2] = fmaf(S[ii + 2], sw[ii + 2], bk2 * vv);
      float br3 = rdlane(rv, ii + 3), bk3 = rdlane(kv, ii + 3);
      y3 = fmaf(br3, S[ii + 3], y3);  S[ii + 3] = fmaf(S[ii + 3], sw[ii + 3], bk3 * vv);
    }
    float yy = ((y0 + y1) + (y2 + y3)) + pl * vv;
    kp[0] = f2b(yy);
    rp += 2048; kp += 2048; vp += 2048;
    rv = rn; kv = kn; vv = vn;
  }
}

// =====================================================================
// GroupNorm per (b,t,h) over HS=64 (with /8 prescale), then * g.
// =====================================================================
__global__ __launch_bounds__(256) void gn_mul(const u16* __restrict__ y,
                                              const float* __restrict__ lnxw,
                                              const float* __restrict__ lnxb,
                                              const u16* __restrict__ g,
                                              u16* __restrict__ og)
{
  const int tid = threadIdx.x;
  const int wv = tid >> 6, j = tid & 63;
  const size_t gidx = (size_t)blockIdx.x * 4 + wv;
  const size_t bt = gidx >> 5;
  const int h = (int)(gidx & 31);
  const int c = h * 64 + j;
  float o = b2f(y[bt * 2048 + c]) * 0.125f;
  float s = o;
#pragma unroll
  for (int off = 32; off; off >>= 1) s += __shfl_xor(s, off, 64);
  const float m = s * (1.f / 64.f);
  const float d = o - m;
  float s2 = d * d;
#pragma unroll
  for (int off = 32; off; off >>= 1) s2 += __shfl_xor(s2, off, 64);
  const float var = s2 * (1.f / 64.f);
  float on = d * rsqrtf(var + 1e-5f);
  on = on * lnxw[c] + lnxb[c];
  og[bt * 2048 + c] = f2b(on * b2f(g[bt * 2048 + c]));
}

// =====================================================================
extern "C" void kernel_launch(void* const* d_in, const int* in_sizes, int n_in,
                              void* d_out, int out_size, void* d_ws, size_t ws_size,
                              hipStream_t stream)
{
  const float* x    = (const float*)d_in[0];
  const float* att0 = (const float*)d_in[1];
  const float* ffn0 = (const float*)d_in[2];
  const float* wkv0 = (const float*)d_in[3];
  const float* ln0w = (const float*)d_in[4];
  const float* ln0b = (const float*)d_in[5];
  const float* ln1w = (const float*)d_in[6];
  const float* ln1b = (const float*)d_in[7];
  const float* ln2w = (const float*)d_in[8];
  const float* ln2b = (const float*)d_in[9];
  const float* tmk  = (const float*)d_in[10];
  const float* tmv  = (const float*)d_in[11];
  const float* tmr  = (const float*)d_in[12];
  const float* tmg  = (const float*)d_in[13];
  const float* td   = (const float*)d_in[14];
  const float* tf   = (const float*)d_in[15];
  const float* Wg   = (const float*)d_in[16];
  const float* Wr   = (const float*)d_in[17];
  const float* Wk   = (const float*)d_in[18];
  const float* Wv   = (const float*)d_in[19];
  const float* Wo   = (const float*)d_in[20];
  const float* lnxw = (const float*)d_in[21];
  const float* lnxb = (const float*)d_in[22];
  const float* ftmk = (const float*)d_in[23];
  const float* ftmr = (const float*)d_in[24];
  const float* fWk  = (const float*)d_in[25];
  const float* fWr  = (const float*)d_in[26];
  const float* fWv  = (const float*)d_in[27];

  // ws layout (u16 elems; 1 MiB = 524288). Peak 320 MiB (known safe).
  u16* ws = (u16*)d_ws;
  auto seg = [&](size_t mib) { return ws + mib * 524288ull; };
  u16* A_ = seg(0);     // x0 -> x1 (bf16)
  u16* B_ = seg(64);
  u16* C_ = seg(128);
  u16* D_ = seg(192);
  u16* WT = seg(256);   // 64 MiB weight region (re-packed per phase)
  u16* w_r = WT;
  u16* w_k = WT + 4194304ull;
  u16* w_v = WT + 8388608ull;
  u16* w_g = WT + 12582912ull;
  u16* w_o = WT + 16777216ull;
  u16* w_fr = WT;
  u16* w_fk = WT + 4194304ull;
  u16* w_fv = WT + 18874368ull;
  u16* KK = C_;         // 56 MiB kk chunk [16384 x 1792] (C_ dead by then)

  float* out_x   = (float*)d_out;
  float* out_ffn = out_x + 33554432ull;
  float* out_att = out_ffn + 16384ull;
  float* out_wkv = out_att + 16384ull;
  u16* OUT0 = (u16*)d_out;              // xg scratch
  u16* OUT1 = OUT0 + 33554432ull;       // rb
  float* wkvloc = (float*)d_out;        // 64 MiB wkv chunk-state buffer

  const dim3 b256(256);
  const dim3 t512(512);
  const dim3 gSq(512);    // (2048/256)*(16384/256)
  const dim3 gFk(448);    // (1792/256)*(16384/256)

  // ---- attention ----
  cvt_f32_bf16<<<4096, b256, 0, stream>>>(Wr, w_r, 1048576);
  cvt_f32_bf16<<<4096, b256, 0, stream>>>(Wk, w_k, 1048576);
  cvt_f32_bf16<<<4096, b256, 0, stream>>>(Wv, w_v, 1048576);
  cvt_f32_bf16<<<4096, b256, 0, stream>>>(Wg, w_g, 1048576);
  cvt_f32_bf16<<<4096, b256, 0, stream>>>(Wo, w_o, 1048576);
  ln_plain<<<16384, b256, 0, stream>>>(x, ln0w, ln0b, A_);
  ln_mix<4><<<16384, b256, 0, stream>>>(A_, ln1w, ln1b, att0, tmk, tmv, tmr, tmg,
                                        B_, C_, D_, OUT0, out_att); // xk,xv,xr,xg
  gemm256<0><<<gSq, t512, 0, stream>>>(D_,   w_r, OUT1, nullptr, nullptr,
                                       16384, 2048, 2048, 2048, 2048, 2048); // rb
  gemm256<0><<<gSq, t512, 0, stream>>>(B_,   w_k, D_,   nullptr, nullptr,
                                       16384, 2048, 2048, 2048, 2048, 2048); // kb
  gemm256<0><<<gSq, t512, 0, stream>>>(C_,   w_v, B_,   nullptr, nullptr,
                                       16384, 2048, 2048, 2048, 2048, 2048); // vb
  gemm256<1><<<gSq, t512, 0, stream>>>(OUT0, w_g, C_,   nullptr, nullptr,
                                       16384, 2048, 2048, 2048, 2048, 2048); // gb (silu)
  wkv_state<<<1024, b256, 0, stream>>>(D_, B_, td, wkvloc);
  wkv_combine<<<256, b256, 0, stream>>>(wkv0, td, wkvloc, out_wkv);
  wkv_y<<<1024, b256, 0, stream>>>(OUT1, D_, B_, td, tf, wkvloc);   // y -> D_
  gn_mul<<<131072, b256, 0, stream>>>(D_, lnxw, lnxb, C_, B_);      // og -> B_
  gemm256<4><<<gSq, t512, 0, stream>>>(B_, w_o, A_, A_, nullptr,
                                       16384, 2048, 2048, 2048, 2048, 2048); // x1 = x0+att

  // ---- ffn ----
  ln_mix<2><<<16384, b256, 0, stream>>>(A_, ln2w, ln2b, ffn0, ftmk, ftmr, nullptr, nullptr,
                                        B_, C_, nullptr, nullptr, out_ffn);  // xk2=B_, xr2=C_
  cvt_f32_bf16<<<4096, b256, 0, stream>>>(fWr, w_fr, 1048576);
  gemm256<3><<<gSq, t512, 0, stream>>>(C_, w_fr, D_, nullptr, nullptr,
                                       16384, 2048, 2048, 2048, 2048, 2048); // rr (sigmoid)
  cvt_f32_bf16<<<14336, b256, 0, stream>>>(fWk, w_fk, 3670016);
  cvt_f32_bf16<<<14336, b256, 0, stream>>>(fWv, w_fv, 3670016);
  // F chunked into 4 x 1792: kk chunk -> KK; kv accumulated f32 in out_x
  for (int c = 0; c < 4; ++c) {
    gemm256<2><<<gFk, t512, 0, stream>>>(B_, w_fk + (size_t)c * 1792 * 2048, KK,
                                         nullptr, nullptr,
                                         16384, 1792, 2048, 2048, 2048, 1792); // kk (relu^2)
    if (c == 0)
      gemm256<6><<<gSq, t512, 0, stream>>>(KK, w_fv + (size_t)c * 1792, out_x,
                                           nullptr, nullptr,
                                           16384, 2048, 1792, 1792, 7168, 2048);
    else if (c < 3)
      gemm256<7><<<gSq, t512, 0, stream>>>(KK, w_fv + (size_t)c * 1792, out_x,
                                           nullptr, nullptr,
                                           16384, 2048, 1792, 1792, 7168, 2048);
    else
      gemm256<8><<<gSq, t512, 0, stream>>>(KK, w_fv + (size_t)c * 1792, out_x,
                                           A_, D_,
                                           16384, 2048, 1792, 1792, 7168, 2048);
  }
}